// Round 5
// baseline (162.422 us; speedup 1.0000x reference)
//
#include <hip/hip_runtime.h>

// ---------------------------------------------------------------------------
// Fused: LN -> qkv GEMM (+fused RoPE epilogue) -> [bilinear + v-transpose]
//        -> flash attn -> out GEMM.  B=1, N=2048, DIM=1024, HEADS=16, DHEAD=64.
// R5: occupancy round.  attn Ps stride 56->40 u16 (LDS 60->52KB, 3 blocks/CU);
//     gemm_qkv 64x128 tiles (768 blocks = 3/CU even, was 384 = 1.5/CU
//     imbalanced).  Numerics unchanged (absmax 2.44e-4 since R1).
// ---------------------------------------------------------------------------

typedef unsigned short u16;
typedef __attribute__((ext_vector_type(4))) float f32x4;
typedef __attribute__((ext_vector_type(8))) __bf16 bf16x8;

struct alignas(8) US4 { u16 x, y, z, w; };

__device__ __forceinline__ u16 f2bf(float f) {
  union { float f; unsigned u; } v; v.f = f;
  unsigned r = v.u + 0x7FFFu + ((v.u >> 16) & 1u);   // RNE
  return (u16)(r >> 16);
}

typedef void GVOID __attribute__((address_space(1)));
typedef void LVOID __attribute__((address_space(3)));

#if defined(__has_builtin)
#if __has_builtin(__builtin_amdgcn_global_load_lds)
#define HAS_GLD_LDS 1
#endif
#endif

__device__ __forceinline__ void gld16(const void* g, void* l) {
#ifdef HAS_GLD_LDS
  __builtin_amdgcn_global_load_lds((GVOID*)(void*)g, (LVOID*)l, 16, 0, 0);
#else
  struct alignas(16) U4 { unsigned a, b, c, d; };
  *(U4*)l = *(const U4*)g;
#endif
}

__device__ __forceinline__ f32x4 MFMA(bf16x8 a, bf16x8 b, f32x4 c) {
  return __builtin_amdgcn_mfma_f32_16x16x32_bf16(a, b, c, 0, 0, 0);
}

// LDS swizzle for 64B-row tiles (32 u16/row, 4 x 16B chunks): logical chunk q
// of row r stored at chunk q ^ ((r>>1)&3).
__device__ __forceinline__ int swz(int r, int q) {   // u16 index
  return r * 32 + ((q ^ ((r >> 1) & 3)) << 3);
}
__device__ __forceinline__ int swz_src_colb(int o) { // byte offset in 64B row
  const int r = o >> 6;
  return ((((o >> 4) & 3) ^ ((r >> 1) & 3)) << 4);
}

// ---------------------------------------------------------------------------
// prep: all 4 weight transposes (+bf16 cast) and LayerNorm in one launch.
// ---------------------------------------------------------------------------
__global__ __launch_bounds__(256) void prep_kernel(
    const float* __restrict__ x, const float* __restrict__ gamma,
    const float* __restrict__ Wq, const float* __restrict__ Wkv,
    const float* __restrict__ Wo, const float* __restrict__ Wb,
    u16* __restrict__ xn, u16* __restrict__ wqkvT, u16* __restrict__ woT,
    u16* __restrict__ wbT) {
  __shared__ __align__(16) float smem[32 * 33];
  const int bid = blockIdx.x, t = threadIdx.x;
  if (bid < 4160) {
    const float* src; u16* dst; int C, R, bx, by;
    if (bid < 1024)      { src = Wq;  dst = wqkvT;              R = 1024; C = 1024; bx = bid & 31; by = bid >> 5; }
    else if (bid < 3072) { int i = bid - 1024; src = Wkv; dst = wqkvT + 1024 * 1024; R = 1024; C = 2048; bx = i & 63; by = i >> 6; }
    else if (bid < 4096) { int i = bid - 3072; src = Wo;  dst = woT; R = 1024; C = 1024; bx = i & 31; by = i >> 5; }
    else { int i = bid - 4096; int h = i >> 2; src = Wb + (size_t)h * 4096; dst = wbT + (size_t)h * 4096; R = 64; C = 64; bx = i & 1; by = (i >> 1) & 1; }
    float (*tile)[33] = (float(*)[33])smem;
    const int c0 = bx * 32, r0 = by * 32;
    const int tx = t & 31, ty = t >> 5;  // 32 x 8
#pragma unroll
    for (int i = 0; i < 4; i++)
      tile[ty + i * 8][tx] = src[(size_t)(r0 + ty + i * 8) * C + c0 + tx];
    __syncthreads();
#pragma unroll
    for (int i = 0; i < 4; i++)
      dst[(size_t)(c0 + ty + i * 8) * R + r0 + tx] = f2bf(tile[tx][ty + i * 8]);
  } else {
    const int n = bid - 4160;
    const int w = t >> 6, lane = t & 63;
    const float4 v = *(const float4*)&x[(size_t)n * 1024 + t * 4];
    float s = v.x + v.y + v.z + v.w;
    float q = v.x * v.x + v.y * v.y + v.z * v.z + v.w * v.w;
#pragma unroll
    for (int off = 32; off; off >>= 1) {
      s += __shfl_down(s, off);
      q += __shfl_down(q, off);
    }
    if (lane == 0) { smem[w] = s; smem[4 + w] = q; }
    __syncthreads();
    s = smem[0] + smem[1] + smem[2] + smem[3];
    q = smem[4] + smem[5] + smem[6] + smem[7];
    const float mean = s * (1.0f / 1024.0f);
    const float var = q * (1.0f / 1024.0f) - mean * mean;
    const float inv = rsqrtf(var + 1e-5f);
    const float4 g = *(const float4*)&gamma[t * 4];
    US4 o;
    o.x = f2bf((v.x - mean) * inv * g.x);
    o.y = f2bf((v.y - mean) * inv * g.y);
    o.z = f2bf((v.z - mean) * inv * g.z);
    o.w = f2bf((v.w - mean) * inv * g.w);
    *(US4*)&xn[(size_t)n * 1024 + t * 4] = o;
  }
}

// ---------------------------------------------------------------------------
// qkv GEMM with fused RoPE epilogue.  C = xn(2048x1024) @ [Wq|Wkv]  -> cols
// [0,1024) q (rope, *0.125), [1024,2048) k (rope), [2048,3072) v (cast).
// R5: 64x128 tile, grid (24, 32) = 768 blocks = 3/CU even.  4 waves 2x2,
// wave = 32x64 (2x4 MFMA).  LDS 12KB.
// ---------------------------------------------------------------------------
__global__ __launch_bounds__(256, 3) void gemm_qkv(
    const u16* __restrict__ A, const u16* __restrict__ B,
    u16* __restrict__ qh, u16* __restrict__ kr, u16* __restrict__ vh) {
  __shared__ u16 As[64 * 32];    // 4KB
  __shared__ u16 Bs[128 * 32];   // 8KB
  const int K = 1024;
  const int t = threadIdx.x;
  const int w = t >> 6, lane = t & 63, quad = lane >> 4, cc = lane & 15;
  const int bm = blockIdx.y << 6, bn = blockIdx.x << 7;
  const int wm = (w >> 1) << 5, wn = (w & 1) << 6;
  const f32x4 fzero = {0.f, 0.f, 0.f, 0.f};
  f32x4 acc[2][4];
#pragma unroll
  for (int i = 0; i < 2; i++)
#pragma unroll
    for (int j = 0; j < 4; j++) acc[i][j] = fzero;

  const char* gA = (const char*)A;
  const char* gB = (const char*)B;
  for (int k0 = 0; k0 < K; k0 += 32) {
    __syncthreads();
    {
      const int oa = t * 16;                    // 4KB A tile
      const int rowa = oa >> 6;
      gld16(gA + (((size_t)(bm + rowa) * K + k0) << 1) + swz_src_colb(oa),
            (char*)As + oa);
#pragma unroll
      for (int i = 0; i < 2; i++) {
        const int ob = (i * 256 + t) * 16;      // 8KB B tile
        const int rowb = ob >> 6;
        gld16(gB + (((size_t)(bn + rowb) * K + k0) << 1) + swz_src_colb(ob),
              (char*)Bs + ob);
      }
    }
    __syncthreads();
    bf16x8 af[2], bfr[4];
#pragma unroll
    for (int mi = 0; mi < 2; mi++)
      af[mi] = *(const bf16x8*)&As[swz(wm + mi * 16 + cc, quad)];
#pragma unroll
    for (int ni = 0; ni < 4; ni++)
      bfr[ni] = *(const bf16x8*)&Bs[swz(wn + ni * 16 + cc, quad)];
#pragma unroll
    for (int mi = 0; mi < 2; mi++)
#pragma unroll
      for (int ni = 0; ni < 4; ni++)
        acc[mi][ni] = MFMA(af[mi], bfr[ni], acc[mi][ni]);
  }

  const int region = blockIdx.x >> 3;  // 0=q, 1=k, 2=v (uniform per block)
  if (region == 2) {
#pragma unroll
    for (int ni = 0; ni < 4; ni++) {
      const int col = bn + wn + ni * 16 + cc;
      const int h = (col >> 6) & 15, d = col & 63;
#pragma unroll
      for (int mi = 0; mi < 2; mi++) {
        const int row0 = bm + wm + mi * 16 + quad * 4;
#pragma unroll
        for (int r = 0; r < 4; r++)
          vh[((size_t)h * 2048 + row0 + r) * 64 + d] = f2bf(acc[mi][ni][r]);
      }
    }
  } else {
    const float sc = (region == 0) ? 0.125f : 1.0f;
    u16* dst = (region == 0) ? qh : kr;
#pragma unroll
    for (int ni = 0; ni < 4; ni++) {
      const int col = bn + wn + ni * 16 + cc;
      const int h = (col >> 6) & 15, d = col & 63;
      const float theta = __expf(-(float)(col & 31) * 0.2878231366242557f);
      const float sgn = (col & 1) ? 1.0f : -1.0f;
#pragma unroll
      for (int mi = 0; mi < 2; mi++) {
        const int row0 = bm + wm + mi * 16 + quad * 4;
#pragma unroll
        for (int r = 0; r < 4; r++) {
          const float val = acc[mi][ni][r];
          const float part = __shfl_xor(val, 1);
          float sv, cv;
          __sincosf(theta * (float)(row0 + r), &sv, &cv);
          dst[((size_t)h * 2048 + row0 + r) * 64 + d] =
              f2bf((val * cv + sgn * part * sv) * sc);
        }
      }
    }
  }
}

// ---------------------------------------------------------------------------
// mid: [0,512) bilinear kth[h] = kr[h](2048x64) @ wbT[h]^T; [512,1024) vtrans.
// ---------------------------------------------------------------------------
__global__ __launch_bounds__(256, 2) void mid_kernel(
    const u16* __restrict__ kr, const u16* __restrict__ wbT,
    u16* __restrict__ kth, const u16* __restrict__ vh, u16* __restrict__ vt) {
  __shared__ __align__(16) u16 smem[4224];
  const int bid = blockIdx.x, t = threadIdx.x;
  if (bid < 512) {
    const int h = bid >> 5, bm = (bid & 31) << 6;
    u16* As = smem;
    u16* Bs = smem + 2048;
    const int w = t >> 6, lane = t & 63, quad = lane >> 4, cc = lane & 15;
    const int wm = (w >> 1) << 5, wn = (w & 1) << 5;
    const f32x4 fzero = {0.f, 0.f, 0.f, 0.f};
    f32x4 acc[2][2];
#pragma unroll
    for (int i = 0; i < 2; i++)
#pragma unroll
      for (int j = 0; j < 2; j++) acc[i][j] = fzero;
    const char* gA = (const char*)(kr + (size_t)h * 2048 * 64);
    const char* gB = (const char*)(wbT + (size_t)h * 4096);
#pragma unroll
    for (int k0 = 0; k0 < 64; k0 += 32) {
      __syncthreads();
      {
        const int o = t * 16;
        const int row = o >> 6, colb = swz_src_colb(o);
        gld16(gA + (((size_t)(bm + row) * 64 + k0) << 1) + colb, (char*)As + o);
        gld16(gB + (((size_t)row * 64 + k0) << 1) + colb, (char*)Bs + o);
      }
      __syncthreads();
      bf16x8 af[2], bfr[2];
#pragma unroll
      for (int mi = 0; mi < 2; mi++)
        af[mi] = *(const bf16x8*)&As[swz(wm + mi * 16 + cc, quad)];
#pragma unroll
      for (int ni = 0; ni < 2; ni++)
        bfr[ni] = *(const bf16x8*)&Bs[swz(wn + ni * 16 + cc, quad)];
#pragma unroll
      for (int mi = 0; mi < 2; mi++)
#pragma unroll
        for (int ni = 0; ni < 2; ni++)
          acc[mi][ni] = MFMA(af[mi], bfr[ni], acc[mi][ni]);
    }
    u16* C = kth + (size_t)h * 2048 * 64;
#pragma unroll
    for (int mi = 0; mi < 2; mi++) {
      const int row = bm + wm + mi * 16 + quad * 4;
#pragma unroll
      for (int ni = 0; ni < 2; ni++) {
        const int col = wn + ni * 16 + cc;
#pragma unroll
        for (int r = 0; r < 4; r++)
          C[(size_t)(row + r) * 64 + col] = f2bf(acc[mi][ni][r]);
      }
    }
  } else {
    const int idx = bid - 512;
    const int h = idx >> 5, j0 = (idx & 31) * 64;
    u16 (*tile)[65] = (u16(*)[65])smem;
    const int tx = t & 63, ty = t >> 6;
    const u16* src = vh + ((size_t)h * 2048 + j0) * 64;
#pragma unroll
    for (int i = 0; i < 16; i++) tile[ty + i * 4][tx] = src[(ty + i * 4) * 64 + tx];
    __syncthreads();
    u16* dst = vt + (size_t)h * 64 * 2048 + j0;
#pragma unroll
    for (int i = 0; i < 16; i++)
      dst[(size_t)(ty + i * 4) * 2048 + tx] = tile[tx][ty + i * 4];
  }
}

// ---------------------------------------------------------------------------
// Flash attention R5.  One block = one head x 64 q-rows; grid 512.
// Wave w owns j-stripe [w*32, w*32+32) of each 128-j tile, ALL 64 q-rows.
// No-max softmax; l via MFMA-with-ones; S^T so P writes are packed b64.
// Ps stride 40 u16 -> LDS 52KB -> 3 blocks/CU.
// ---------------------------------------------------------------------------
__global__ __launch_bounds__(256, 3) void attn_kernel(
    const u16* __restrict__ qh, const u16* __restrict__ kth,
    const u16* __restrict__ vt, u16* __restrict__ aout) {
  __shared__ u16 Ks[2 * 128 * 32];   // 16KB: K [dsub][j 128][d 32]; Q first; merge: O-half A [e64][q64] f32
  __shared__ u16 Vs[4 * 64 * 32];    // 16KB: V [jsub][e 64][j 32]; merge: O-half B
  __shared__ u16 Ps[4 * 64 * 40];    // 20KB: per-wave P [q 64][j 32, stride 40]; merge: l partials
  const int t = threadIdx.x;
  const int w = t >> 6, lane = t & 63, quad = lane >> 4, cc = lane & 15;
  const int bid = blockIdx.x;
  const int h = (bid & 7) + ((bid >> 8) << 3);   // XCD-aware head mapping
  const int q0 = ((bid >> 3) & 31) << 6;
  const size_t hq = (size_t)h * (2048 * 64);
  const f32x4 fzero = {0.f, 0.f, 0.f, 0.f};

  bf16x8 ones;
  {
    union { u16 u; __bf16 b; } one; one.u = 0x3F80;  // bf16 1.0
#pragma unroll
    for (int i = 0; i < 8; i++) ones[i] = one.b;
  }

  // ---- stage Q (64x64) into Ks as [dsub2][q64][d32]; hoist B-frags ----
#pragma unroll
  for (int i = 0; i < 2; i++) {
    const int o = (i * 256 + t) * 16;
    const int sub = o >> 12, row = (o >> 6) & 63, colb = swz_src_colb(o);
    gld16((const char*)qh + ((hq + (size_t)(q0 + row) * 64 + sub * 32) << 1) + colb,
          (char*)Ks + o);
  }
  __syncthreads();
  bf16x8 qf[4][2];
#pragma unroll
  for (int qn = 0; qn < 4; qn++)
#pragma unroll
    for (int ds = 0; ds < 2; ds++)
      qf[qn][ds] = *(const bf16x8*)&Ks[swz(ds * 64 + qn * 16 + cc, quad)];

  f32x4 oacc[4][4];   // [q-tile][e-tile]
  f32x4 lacc[4];
#pragma unroll
  for (int mi = 0; mi < 4; mi++) {
    lacc[mi] = fzero;
#pragma unroll
    for (int et = 0; et < 4; et++) oacc[mi][et] = fzero;
  }

  for (int jt = 0; jt < 16; jt++) {
    const int j0 = jt << 7;
    __syncthreads();
#pragma unroll
    for (int i = 0; i < 4; i++) {
      const int o = (i * 256 + t) * 16;
      const int colb = swz_src_colb(o);
      const int sub = o >> 13, row = (o >> 6) & 127;
      gld16((const char*)kth + ((hq + (size_t)(j0 + row) * 64 + sub * 32) << 1) + colb,
            (char*)Ks + o);
      const int vsub = o >> 12, vrow = (o >> 6) & 63;
      gld16((const char*)vt + ((hq + (size_t)vrow * 2048 + j0 + vsub * 32) << 1) + colb,
            (char*)Vs + o);
    }
    __syncthreads();

    // ---- S^T = K(32j x 64d) x Q^T(64d x 64q); P = exp(S), packed b64 ----
#pragma unroll
    for (int jm = 0; jm < 2; jm++) {
      const bf16x8 kf0 = *(const bf16x8*)&Ks[swz(w * 32 + jm * 16 + cc, quad)];
      const bf16x8 kf1 = *(const bf16x8*)&Ks[swz(128 + w * 32 + jm * 16 + cc, quad)];
#pragma unroll
      for (int qn = 0; qn < 4; qn++) {
        f32x4 s = MFMA(kf0, qf[qn][0], fzero);
        s = MFMA(kf1, qf[qn][1], s);
        uint2 pk;
        pk.x = (unsigned)f2bf(__expf(s[0])) | ((unsigned)f2bf(__expf(s[1])) << 16);
        pk.y = (unsigned)f2bf(__expf(s[2])) | ((unsigned)f2bf(__expf(s[3])) << 16);
        *(uint2*)&Ps[(w * 64 + qn * 16 + cc) * 40 + jm * 16 + quad * 4] = pk;
      }
    }

    // ---- O += P*V, l += P*1 ----
    bf16x8 vf[4];
#pragma unroll
    for (int et = 0; et < 4; et++)
      vf[et] = *(const bf16x8*)&Vs[swz(w * 64 + et * 16 + cc, quad)];
#pragma unroll
    for (int mi = 0; mi < 4; mi++) {
      const bf16x8 pa = *(const bf16x8*)&Ps[(w * 64 + mi * 16 + cc) * 40 + quad * 8];
      lacc[mi] = MFMA(pa, ones, lacc[mi]);
#pragma unroll
      for (int et = 0; et < 4; et++) oacc[mi][et] = MFMA(pa, vf[et], oacc[mi][et]);
    }
  }

  // ---- merge the 4 wave-partials (additive: no-max softmax) ----
  float* OA = (float*)Ks;   // [e 64][q 64] f32
  float* OB = (float*)Vs;
  float* lP = (float*)Ps;   // [0,64) lA | [64,128) lB | [128,192) l2 | [192,256) l3
  __syncthreads();
  if (w >= 2) {
    float* dst = (w == 2) ? OA : OB;
#pragma unroll
    for (int mi = 0; mi < 4; mi++) {
#pragma unroll
      for (int et = 0; et < 4; et++)
        *(f32x4*)&dst[(et * 16 + cc) * 64 + mi * 16 + quad * 4] = oacc[mi][et];
      if (cc == 0)
#pragma unroll
        for (int r = 0; r < 4; r++)
          lP[64 * w + mi * 16 + quad * 4 + r] = lacc[mi][r];
    }
  }
  __syncthreads();
  if (w < 2) {
    const float* src = (w == 0) ? OA : OB;
    const float* lsrc = &lP[64 * (w + 2)];
#pragma unroll
    for (int mi = 0; mi < 4; mi++) {
#pragma unroll
      for (int et = 0; et < 4; et++)
        oacc[mi][et] += *(const f32x4*)&src[(et * 16 + cc) * 64 + mi * 16 + quad * 4];
#pragma unroll
      for (int r = 0; r < 4; r++)
        lacc[mi][r] += lsrc[mi * 16 + quad * 4 + r];
    }
  }
  __syncthreads();
  if (w < 2) {
    float* dst = (w == 0) ? OA : OB;
#pragma unroll
    for (int mi = 0; mi < 4; mi++) {
#pragma unroll
      for (int et = 0; et < 4; et++)
        *(f32x4*)&dst[(et * 16 + cc) * 64 + mi * 16 + quad * 4] = oacc[mi][et];
      if (cc == 0)
#pragma unroll
        for (int r = 0; r < 4; r++)
          lP[64 * w + mi * 16 + quad * 4 + r] = lacc[mi][r];
    }
  }
  __syncthreads();
  {
    const int q = lane;
    const float linv = 1.0f / (lP[q] + lP[64 + q]);
    u16 obuf[16];
#pragma unroll
    for (int e = 0; e < 16; e++) {
      const int ee = w * 16 + e;
      obuf[e] = f2bf((OA[ee * 64 + q] + OB[ee * 64 + q]) * linv);
    }
    uint4* dst = (uint4*)&aout[(size_t)(q0 + q) * 1024 + h * 64 + w * 16];
    dst[0] = *(uint4*)&obuf[0];
    dst[1] = *(uint4*)&obuf[8];
  }
}

// ---------------------------------------------------------------------------
// out = aout(2048x1024 bf16) @ Wo -> f32.  64x64 tiles, 512 blocks.
// ---------------------------------------------------------------------------
__global__ __launch_bounds__(256, 2) void gemm64_bt_f32(
    const u16* __restrict__ A, const u16* __restrict__ B, float* __restrict__ C,
    int M, int N, int K) {
  __shared__ u16 As[64 * 32];
  __shared__ u16 Bs[64 * 32];
  const int t = threadIdx.x;
  const int w = t >> 6, lane = t & 63, quad = lane >> 4, cc = lane & 15;
  const int bm = blockIdx.y << 6, bn = blockIdx.x << 6;
  const int wm = (w >> 1) << 5, wn = (w & 1) << 5;
  const f32x4 fzero = {0.f, 0.f, 0.f, 0.f};
  f32x4 acc[2][2];
#pragma unroll
  for (int i = 0; i < 2; i++)
#pragma unroll
    for (int j = 0; j < 2; j++) acc[i][j] = fzero;

  const char* gA = (const char*)A;
  const char* gB = (const char*)B;
  for (int k0 = 0; k0 < K; k0 += 32) {
    __syncthreads();
    {
      const int o = t * 16;
      const int row = o >> 6, colb = swz_src_colb(o);
      gld16(gA + (((size_t)(bm + row) * K + k0) << 1) + colb, (char*)As + o);
      gld16(gB + (((size_t)(bn + row) * K + k0) << 1) + colb, (char*)Bs + o);
    }
    __syncthreads();
    bf16x8 af[2], bfr[2];
#pragma unroll
    for (int mi = 0; mi < 2; mi++)
      af[mi] = *(const bf16x8*)&As[swz(wm + mi * 16 + cc, quad)];
#pragma unroll
    for (int ni = 0; ni < 2; ni++)
      bfr[ni] = *(const bf16x8*)&Bs[swz(wn + ni * 16 + cc, quad)];
#pragma unroll
    for (int mi = 0; mi < 2; mi++)
#pragma unroll
      for (int ni = 0; ni < 2; ni++)
        acc[mi][ni] = MFMA(af[mi], bfr[ni], acc[mi][ni]);
  }
#pragma unroll
  for (int mi = 0; mi < 2; mi++) {
    const int row = bm + wm + mi * 16 + quad * 4;
#pragma unroll
    for (int ni = 0; ni < 2; ni++) {
      const int col = bn + wn + ni * 16 + cc;
#pragma unroll
      for (int r = 0; r < 4; r++) C[(size_t)(row + r) * N + col] = acc[mi][ni][r];
    }
  }
}

// ---------------------------------------------------------------------------
// host side
// ---------------------------------------------------------------------------
extern "C" void kernel_launch(void* const* d_in, const int* in_sizes, int n_in,
                              void* d_out, int out_size, void* d_ws, size_t ws_size,
                              hipStream_t stream) {
  (void)in_sizes; (void)n_in; (void)out_size; (void)ws_size;
  const float* x     = (const float*)d_in[0];
  const float* gamma = (const float*)d_in[1];
  const float* Wq    = (const float*)d_in[2];
  const float* Wkv   = (const float*)d_in[3];
  const float* Wb    = (const float*)d_in[4];
  const float* Wo    = (const float*)d_in[5];
  float* out = (float*)d_out;
  char* ws = (char*)d_ws;

  const size_t OFF_XN    = 0;
  const size_t OFF_WQKVT = 4194304;
  const size_t OFF_WOT   = 10485760;
  const size_t OFF_WBT   = 12582912;
  const size_t OFF_QH    = 12713984;
  const size_t OFF_KR    = 16908288;
  const size_t OFF_KTH   = 21102592;
  const size_t OFF_VH    = 25296896;
  const size_t OFF_VT    = 29491200;
  const size_t OFF_AOUT  = 33685504;   // end 37879808

  u16* xn    = (u16*)(ws + OFF_XN);
  u16* wqkvT = (u16*)(ws + OFF_WQKVT);
  u16* woT   = (u16*)(ws + OFF_WOT);
  u16* wbT   = (u16*)(ws + OFF_WBT);
  u16* qh    = (u16*)(ws + OFF_QH);
  u16* kr    = (u16*)(ws + OFF_KR);
  u16* kth   = (u16*)(ws + OFF_KTH);
  u16* vh    = (u16*)(ws + OFF_VH);
  u16* vt    = (u16*)(ws + OFF_VT);
  u16* aout  = (u16*)(ws + OFF_AOUT);

  prep_kernel<<<6208, 256, 0, stream>>>(x, gamma, Wq, Wkv, Wo, Wb,
                                        xn, wqkvT, woT, wbT);
  gemm_qkv<<<dim3(24, 32), 256, 0, stream>>>(xn, wqkvT, qh, kr, vh);
  mid_kernel<<<1024, 256, 0, stream>>>(kr, wbT, kth, vh, vt);
  attn_kernel<<<512, 256, 0, stream>>>(qh, kth, vt, aout);
  gemm64_bt_f32<<<dim3(16, 32), 256, 0, stream>>>(aout, woT, out, 2048, 1024, 1024);
}